// Round 14
// baseline (223.867 us; speedup 1.0000x reference)
//
#include <hip/hip_runtime.h>
#include <stdint.h>

#define Bz 8
#define Tz 1024
#define Cz 768
#define NHz 12
#define HDz 64

typedef unsigned short u16;
typedef __attribute__((ext_vector_type(8))) __bf16 bf16x8;
typedef __attribute__((ext_vector_type(4))) float f32x4;
typedef __attribute__((ext_vector_type(4))) unsigned int u32x4;

__device__ __forceinline__ float bf2f(u16 b) {
    union { uint32_t u; float f; } c; c.u = ((uint32_t)b) << 16; return c.f;
}
__device__ __forceinline__ u16 f2bf(float f) {
    union { float f; uint32_t u; } c; c.f = f;
    uint32_t u = c.u;
    return (u16)((u + 0x7fffu + ((u >> 16) & 1u)) >> 16);
}
__device__ __forceinline__ u16 f2bf_hw(float f) {   // native RTNE cast
    __bf16 b = (__bf16)f;
    union { __bf16 b; u16 u; } c; c.b = b; return c.u;
}

// s_waitcnt helpers: wait vmcnt<=VM (lgkm/exp unconstrained), and lgkm==0 only.
// simm16 = vm[3:0] | exp(3b)<<4 | lgkm(4b)<<8 | vm[5:4]<<14
template<unsigned VM>
__device__ __forceinline__ void wait_vm() {
    __builtin_amdgcn_s_waitcnt((VM & 15u) | (7u << 4) | (15u << 8) | ((VM >> 4) << 14));
}
__device__ __forceinline__ void wait_lgkm0() {
    __builtin_amdgcn_s_waitcnt(15u | (7u << 4) | (0u << 8) | (3u << 14));
}

// ---------------------------------------------------------------------------
// Fused fp32 -> bf16 elementwise convert for all 4 input tensors (1 launch).
// ---------------------------------------------------------------------------
#define N4_X  (Bz * Tz * Cz / 4)
#define N4_WV (Cz * Cz / 4)
#define N4_WC (Tz * Tz / 4)
#define N4_WP (Cz * Cz / 4)
#define N4_ALL (N4_X + N4_WV + N4_WC + N4_WP)

__global__ __launch_bounds__(256)
void cvt_all(const float* __restrict__ x, const float* __restrict__ wv,
             const float* __restrict__ wc, const float* __restrict__ wp,
             u16* __restrict__ xb, u16* __restrict__ wvb,
             u16* __restrict__ wcb, u16* __restrict__ wpb) {
    int i = blockIdx.x * 256 + threadIdx.x;
    if (i >= N4_ALL) return;
    const float* in;
    u16* out;
    if (i < N4_X) {
        in = x; out = xb;
    } else if (i < N4_X + N4_WV) {
        in = wv; out = wvb; i -= N4_X;
    } else if (i < N4_X + N4_WV + N4_WC) {
        in = wc; out = wcb; i -= N4_X + N4_WV;
    } else {
        in = wp; out = wpb; i -= N4_X + N4_WV + N4_WC;
    }
    float4 v = ((const float4*)in)[i];
    union { u16 h[4]; uint2 u; } o;
    o.h[0] = f2bf(v.x); o.h[1] = f2bf(v.y); o.h[2] = f2bf(v.z); o.h[3] = f2bf(v.w);
    ((uint2*)out)[i] = o.u;
}

// ---------------------------------------------------------------------------
// C = alpha * (A . B^T) [+ bias_col]   MFMA 16x16x32, all-bf16 operands.
// R13 theory: GEMMs are TLP-starved (64x64/wave => 6 waves/CU for the
// M=8192,N=768 shapes; 1 wave/CU for 1024^2). Wave tile generalized to
// MT x NTC 16x16 fragments; 32x32/wave quadruples waves: 24/CU (steps
// 3/5/7) and 4/CU (step 2). MFMA:ds_read drops to 1:1 but LDS/L2 floors
// for these shapes are ~4-9us -- latency hiding dominates.
// BK=64 + counted-vmcnt pipeline (R13-measured win, kept):
//   reads->lgkm0+barrier(WAR)->stage(t+2)->MFMA->vm(LD)->barrier.
// A/B staged with global-source chunk XOR swizzle; readers XOR back.
// ---------------------------------------------------------------------------
template<int BM, int BN, int WM, int WN, int MT, int NTC, bool OUTF32, bool HASBIAS>
__global__ __launch_bounds__(WM * WN * 64)
void gemm_bt(const u16* __restrict__ A, long long sAz, int lda,
             const u16* __restrict__ Bp, long long sBz, int ldb,
             void* __restrict__ Cp, long long sCz, int ldc,
             const float* __restrict__ bias, int K, float alpha) {
    constexpr int NT = WM * WN * 64;
    constexpr int BK = 64;
    constexpr int AI = (BM * BK) / (NT * 8);
    constexpr int BI = (BN * BK) / (NT * 8);
    constexpr unsigned LD = AI + BI;           // gload_lds per stage()
    constexpr int WR = MT * 16;                // wave tile rows
    constexpr int WC = NTC * 16;               // wave tile cols
    static_assert(AI >= 1 && (BM * BK) % (NT * 8) == 0, "A staging");
    static_assert(BI >= 1 && (BN * BK) % (NT * 8) == 0, "B staging");
    static_assert(BM == WM * WR && BN == WN * WC, "wave tiling");

    __shared__ alignas(16) u16 As[2][BM * BK];
    __shared__ alignas(16) u16 Bs[2][BN * BK];

    const int z = blockIdx.z;
    const u16* Ag = A + (long long)z * sAz;
    const u16* Bg = Bp + (long long)z * sBz;

    const int tid = threadIdx.x;
    const int lane = tid & 63;
    const int w = tid >> 6;
    const int wm = w / WN;
    const int wn = w % WN;
    const int rowBase = blockIdx.y * BM;
    const int colBase = blockIdx.x * BN;
    const int quad = lane >> 4;
    const int frow = lane & 15;

    auto stage = [&](int buf, int k0) {
#pragma unroll
        for (int i = 0; i < AI; i++) {
            int e = (i * NT + tid) * 8;
            int row = e >> 6;
            int gcol = (((e & 63) >> 3) ^ (row & 7)) * 8;   // src-side swizzle
            const u16* g = Ag + (long long)(rowBase + row) * lda + k0 + gcol;
            __builtin_amdgcn_global_load_lds(
                (const __attribute__((address_space(1))) uint32_t*)g,
                (__attribute__((address_space(3))) uint32_t*)(&As[buf][0] + e), 16, 0, 0);
        }
#pragma unroll
        for (int i = 0; i < BI; i++) {
            int e = (i * NT + tid) * 8;
            int row = e >> 6;
            int gcol = (((e & 63) >> 3) ^ (row & 7)) * 8;
            const u16* g = Bg + (long long)(colBase + row) * ldb + k0 + gcol;
            __builtin_amdgcn_global_load_lds(
                (const __attribute__((address_space(1))) uint32_t*)g,
                (__attribute__((address_space(3))) uint32_t*)(&Bs[buf][0] + e), 16, 0, 0);
        }
    };

    f32x4 acc[MT][NTC] = {};

    const int nk = K / BK;
    stage(0, 0);
    if (nk > 1) { stage(1, BK); wait_vm<LD>(); }   // tile0 landed; tile1 in flight
    else        { wait_vm<0>(); }
    __builtin_amdgcn_s_barrier();                  // all waves' tile0 landed

#pragma unroll 1
    for (int t = 0; t < nk; ++t) {
        const int cur = t & 1;

        // read ALL fragments of tile t into regs
        bf16x8 af[2][MT], bfr[2][NTC];
#pragma unroll
        for (int kk = 0; kk < 2; kk++) {
#pragma unroll
            for (int mt = 0; mt < MT; mt++) {
                int row = wm * WR + mt * 16 + frow;
                af[kk][mt] = *(const bf16x8*)&As[cur][row * 64 + (((kk * 4 + quad) ^ (frow & 7)) * 8)];
            }
#pragma unroll
            for (int nt = 0; nt < NTC; nt++) {
                int row = wn * WC + nt * 16 + frow;
                bfr[kk][nt] = *(const bf16x8*)&Bs[cur][row * 64 + (((kk * 4 + quad) ^ (frow & 7)) * 8)];
            }
        }
        wait_lgkm0();                              // our reads retired to regs
        __builtin_amdgcn_s_barrier();              // all waves done reading buf[cur]

        if (t + 2 < nk) stage(cur, (t + 2) * BK);  // overwrite freed buffer

#pragma unroll
        for (int kk = 0; kk < 2; kk++)
#pragma unroll
            for (int mt = 0; mt < MT; mt++)
#pragma unroll
                for (int nt = 0; nt < NTC; nt++)
                    acc[mt][nt] = __builtin_amdgcn_mfma_f32_16x16x32_bf16(
                        af[kk][mt], bfr[kk][nt], acc[mt][nt], 0, 0, 0);

        if (t + 2 < nk)       wait_vm<LD>();       // tile t+1 landed; t+2 in flight
        else if (t + 1 < nk)  wait_vm<0>();        // last prefetch landed
        if (t + 1 < nk) __builtin_amdgcn_s_barrier();
    }

    const int r0 = rowBase + wm * WR;
    const int c0 = colBase + wn * WC;
    const int rl = (lane >> 4) * 4;
    const int cl = lane & 15;
#pragma unroll
    for (int mt = 0; mt < MT; mt++) {
#pragma unroll
        for (int nt = 0; nt < NTC; nt++) {
#pragma unroll
            for (int r = 0; r < 4; r++) {
                int row = r0 + mt * 16 + rl + r;
                int col = c0 + nt * 16 + cl;
                float v = acc[mt][nt][r] * alpha;
                if (HASBIAS) v += bias[col];
                if (OUTF32)
                    ((float*)Cp)[(long long)z * sCz + (long long)row * ldc + col] = v;
                else
                    ((u16*)Cp)[(long long)z * sCz + (long long)row * ldc + col] = f2bf_hw(v);
            }
        }
    }
}

// ---------------------------------------------------------------------------
// Transpose to bf16: in [rows,cols] (fp32 if INF32 else bf16) -> [cols,rows].
// ---------------------------------------------------------------------------
template<bool INF32>
__global__ __launch_bounds__(256)
void transpose_to_bf16(const void* __restrict__ in, u16* __restrict__ out,
                       int rows, int cols, long long sInZ, long long sOutZ) {
    __shared__ u16 tile[32][33];
    const int z = blockIdx.z;
    const int c0 = blockIdx.x * 32, r0 = blockIdx.y * 32;
    const int tx = threadIdx.x, ty = threadIdx.y;
#pragma unroll
    for (int i = 0; i < 32; i += 8) {
        long long off = (long long)z * sInZ + (long long)(r0 + ty + i) * cols + c0 + tx;
        tile[ty + i][tx] = INF32 ? f2bf(((const float*)in)[off]) : ((const u16*)in)[off];
    }
    __syncthreads();
#pragma unroll
    for (int i = 0; i < 32; i += 8)
        out[(long long)z * sOutZ + (long long)(c0 + ty + i) * rows + r0 + tx] = tile[tx][ty + i];
}

// ---------------------------------------------------------------------------
// Fused flash attention v8 (unchanged; R12 measured 46.8, R13 52.4 on the
// same binary -> +-10% run noise on this harness). Held for attribution.
// ---------------------------------------------------------------------------
#define LOG2E 1.44269504f

__global__ __launch_bounds__(512)
void flash_attn(const u16* __restrict__ v, const u16* __restrict__ U,
                const u16* __restrict__ vT, const float* __restrict__ bc,
                u16* __restrict__ y) {
    __shared__ alignas(16) u16 Us[128 * 64];    // [key][chunk^key&7] (swizzled)
    __shared__ alignas(16) u16 Vs[64 * 128];    // [dim][chunk^dim&15] (swizzled)
    __shared__ alignas(16) u16 Ps[128 * 136];   // q x keys, stride 136
    __shared__ u16 bcs[Tz];                     // bf16(bc * log2e)

    // grid remap: 768 = 8 xcd x 96 slots; xcd-affine columns, heavy qi first
    const int bi = blockIdx.x;
    const int xcd = bi & 7;
    const int slot = bi >> 3;                   // 0..95
    const int col = (slot % 12) * 8 + xcd;      // 0..95, col%8 == xcd
    const int qi = 7 - slot / 12;               // 0..7, heavy tiles first
    const int b = col / NHz, h = col % NHz;

    const int tid = threadIdx.x, lane = tid & 63, w = tid >> 6;
    const int quad = lane >> 4, cl = lane & 15;
    const int q0 = qi * 128;
    const int wrow = w * 16;                    // wave's 16 q-rows (w 0..7)

    for (int j = tid; j < Tz; j += 512) bcs[j] = f2bf(bc[j] * LOG2E);

    // resident A-fragments of vq (this block's own 128x64 slice)
    const u16* vq = v + ((long long)b * Tz + q0) * Cz + h * HDz;
    bf16x8 aS[2];
#pragma unroll
    for (int ks = 0; ks < 2; ks++)
        aS[ks] = *(const bf16x8*)(vq + (long long)(wrow + cl) * Cz + ks * 32 + quad * 8);

    f32x4 Oacc[4] = {};
    float mrow[4], lrow[4];
#pragma unroll
    for (int r = 0; r < 4; r++) { mrow[r] = -3.0e38f; lrow[r] = 0.f; }

    const u16* Ub = U + (long long)b * Tz * Cz + h * HDz;
    const u16* Vb = vT + ((long long)b * Cz + h * HDz) * Tz;

    __syncthreads();   // bcs visible; drains pre-loop VMEM

    const int kts = qi + 1;   // # of 128-wide k-tiles covering [0, q0+128)
    for (int kt = 0; kt < kts; kt++) {
        if (kt) __builtin_amdgcn_s_barrier();   // WAR: all waves done with Us/Vs
        const u16* Ug = Ub + (long long)kt * 128 * Cz;
#pragma unroll
        for (int i = 0; i < 2; i++) {           // Us first (waited by vmcnt(2))
            int e = (i * 512 + tid) * 8;
            int key = e >> 6;
            int ch = ((e & 63) >> 3) ^ (key & 7);   // global-side swizzle
            __builtin_amdgcn_global_load_lds(
                (const __attribute__((address_space(1))) uint32_t*)(Ug + (long long)key * Cz + ch * 8),
                (__attribute__((address_space(3))) uint32_t*)(Us + e), 16, 0, 0);
        }
        const u16* Vg = Vb + kt * 128;
#pragma unroll
        for (int i = 0; i < 2; i++) {           // Vs second (stays in flight)
            int e = (i * 512 + tid) * 8;
            int dim = e >> 7;
            int ch = ((e & 127) >> 3) ^ (dim & 15);  // global-side swizzle
            __builtin_amdgcn_global_load_lds(
                (const __attribute__((address_space(1))) uint32_t*)(Vg + (long long)dim * Tz + ch * 8),
                (__attribute__((address_space(3))) uint32_t*)(Vs + e), 16, 0, 0);
        }
        // own Us landed (in-order retire); Vs (newest 2) may still be in flight
        asm volatile("s_waitcnt vmcnt(2)" ::: "memory");
        __builtin_amdgcn_s_barrier();           // all waves' Us landed

        // S = vq . Uk^T  (wave tile 16 x 128) — overlaps Vs flight time
        f32x4 S[8] = {};
        __builtin_amdgcn_s_setprio(1);
#pragma unroll
        for (int ks = 0; ks < 2; ks++)
#pragma unroll
            for (int nt = 0; nt < 8; nt++) {
                int key = nt * 16 + cl;
                bf16x8 bS = *(const bf16x8*)&Us[key * 64 + (((ks * 4 + quad) ^ (key & 7)) * 8)];
                S[nt] = __builtin_amdgcn_mfma_f32_16x16x32_bf16(aS[ks], bS, S[nt], 0, 0, 0);
            }
        __builtin_amdgcn_s_setprio(0);

        const bool last = (kt == kts - 1);
#pragma unroll
        for (int nt = 0; nt < 8; nt++) {
            float bl = bf2f(bcs[kt * 128 + nt * 16 + cl]);
#pragma unroll
            for (int r = 0; r < 4; r++)
                S[nt][r] = S[nt][r] * (0.125f * LOG2E) + bl;
        }
        if (last) {                             // uniform branch: mask fixup
            int rowg = q0 + wrow + quad * 4;
#pragma unroll
            for (int nt = 0; nt < 8; nt++) {
                int colg = kt * 128 + nt * 16 + cl;
#pragma unroll
                for (int r = 0; r < 4; r++)
                    if (colg > rowg + r) S[nt][r] = -3.0e38f;
            }
        }

        // row max (regs, then across the 16 lanes of the quad group)
        float mnew[4], alpha[4];
#pragma unroll
        for (int r = 0; r < 4; r++) {
            float m = S[0][r];
#pragma unroll
            for (int nt = 1; nt < 8; nt++) m = fmaxf(m, S[nt][r]);
#pragma unroll
            for (int d = 1; d < 16; d <<= 1) m = fmaxf(m, __shfl_xor(m, d));
            mnew[r] = fmaxf(mrow[r], m);
            alpha[r] = __builtin_amdgcn_exp2f(mrow[r] - mnew[r]);
            mrow[r] = mnew[r];
        }

        // P = exp2(S - m) -> LDS (wave-private rows), accumulate row sums
        float psum[4] = {};
#pragma unroll
        for (int nt = 0; nt < 8; nt++)
#pragma unroll
            for (int r = 0; r < 4; r++) {
                float p = __builtin_amdgcn_exp2f(S[nt][r] - mnew[r]);
                psum[r] += p;
                Ps[(wrow + quad * 4 + r) * 136 + nt * 16 + cl] = f2bf_hw(p);
            }
#pragma unroll
        for (int r = 0; r < 4; r++) {
            float s = psum[r];
#pragma unroll
            for (int d = 1; d < 16; d <<= 1) s += __shfl_xor(s, d);
            lrow[r] = lrow[r] * alpha[r] + s;
#pragma unroll
            for (int nt2 = 0; nt2 < 4; nt2++)
                Oacc[nt2][r] *= alpha[r];
        }

        // own Vs landed; barrier -> all waves' Vs landed
        asm volatile("s_waitcnt vmcnt(0)" ::: "memory");
        __builtin_amdgcn_s_barrier();

        // O += P . Vk   (K = 128)
        __builtin_amdgcn_s_setprio(1);
#pragma unroll
        for (int ks = 0; ks < 4; ks++) {
            bf16x8 pA = *(const bf16x8*)&Ps[(wrow + cl) * 136 + ks * 32 + quad * 8];
#pragma unroll
            for (int nt2 = 0; nt2 < 4; nt2++) {
                int dim = nt2 * 16 + cl;
                bf16x8 vB = *(const bf16x8*)&Vs[dim * 128 + (((ks * 4 + quad) ^ cl) * 8)];
                Oacc[nt2] = __builtin_amdgcn_mfma_f32_16x16x32_bf16(pA, vB, Oacc[nt2], 0, 0, 0);
            }
        }
        __builtin_amdgcn_s_setprio(0);
    }

    // epilogue: O /= l, write y (in-place into v's own region)
    u16* yq = y + ((long long)b * Tz + q0) * Cz + h * HDz;
#pragma unroll
    for (int r = 0; r < 4; r++) {
        float inv = 1.f / lrow[r];
#pragma unroll
        for (int nt2 = 0; nt2 < 4; nt2++)
            yq[(long long)(wrow + quad * 4 + r) * Cz + nt2 * 16 + cl] =
                f2bf_hw(Oacc[nt2][r] * inv);
    }
}

// ---------------------------------------------------------------------------
extern "C" void kernel_launch(void* const* d_in, const int* in_sizes, int n_in,
                              void* d_out, int out_size, void* d_ws, size_t ws_size,
                              hipStream_t stream) {
    const float* x  = (const float*)d_in[0];
    const float* Wv = (const float*)d_in[1];
    const float* bv = (const float*)d_in[2];
    const float* Wl = (const float*)d_in[3];
    const float* Wc = (const float*)d_in[4];
    const float* bc = (const float*)d_in[5];
    const float* Wp = (const float*)d_in[6];
    const float* bp = (const float*)d_in[7];

    // ws (bf16 elems, ~59 MB): xb, Wvb, Wcb, Wpb, WlT, Wcl, vbf, vT, U
    u16* ws  = (u16*)d_ws;
    u16* xb  = ws;
    u16* Wvb = xb  + (size_t)Bz * Tz * Cz;
    u16* Wcb = Wvb + (size_t)Cz * Cz;
    u16* Wpb = Wcb + (size_t)Tz * Tz;
    u16* WlT = Wpb + (size_t)Cz * Cz;
    u16* Wcl = WlT + (size_t)Tz * Tz;
    u16* vbf = Wcl + (size_t)Tz * Tz;
    u16* vT  = vbf + (size_t)Bz * Tz * Cz;
    u16* U   = vT  + (size_t)Bz * Tz * Cz;

    const long long sTC = (long long)Tz * Cz;
    const long long sCT = (long long)Cz * Tz;

    // 0) one-time bf16 conversions (single fused launch)
    cvt_all<<<(N4_ALL + 255) / 256, 256, 0, stream>>>(x, Wv, Wc, Wp, xb, Wvb, Wcb, Wpb);
    // 1) WlT = Wl^T (fp32 -> bf16)
    transpose_to_bf16<true><<<dim3(32, 32, 1), dim3(32, 8), 0, stream>>>(Wl, WlT, Tz, Tz, 0, 0);
    // 2) Wcl = Wcb . WlT^T = Wc @ Wl — 64^2 block / 4 waves of 32x32:
    //    256 blocks, 4 waves/CU (was 1 wave/CU)
    gemm_bt<64, 64, 2, 2, 2, 2, false, false><<<dim3(Tz / 64, Tz / 64, 1), 256, 0, stream>>>(
        Wcb, 0, Tz, WlT, 0, Tz, Wcl, 0, Tz, nullptr, Tz, 1.f);
    // 3) v = xb . Wvb^T + bv — 64^2 / 32x32 waves: 1536 blocks, 24 waves/CU
    gemm_bt<64, 64, 2, 2, 2, 2, false, true><<<dim3(Cz / 64, (Bz * Tz) / 64, 1), 256, 0, stream>>>(
        xb, 0, Cz, Wvb, 0, Cz, vbf, 0, Cz, bv, Cz, 1.f);
    // 4) vT[b] = v[b]^T
    transpose_to_bf16<false><<<dim3(Cz / 32, Tz / 32, Bz), dim3(32, 8), 0, stream>>>(
        vbf, vT, Tz, Cz, sTC, sCT);
    // 5) U[b] = Wcl @ v[b]  (= Wcl . vT[b]^T), K=T — 64^2 / 32x32 waves
    gemm_bt<64, 64, 2, 2, 2, 2, false, false><<<dim3(Cz / 64, Tz / 64, Bz), 256, 0, stream>>>(
        Wcl, 0, Tz, vT, sCT, Tz, U, sTC, Cz, nullptr, Tz, 1.f);
    // 6) fused logits -> causal softmax -> P.V, y in-place into vbf
    flash_attn<<<dim3(8 * NHz * Bz, 1, 1), 512, 0, stream>>>(vbf, U, vT, bc, vbf);
    // 7) out = y . Wpb^T + bp  (fp32 out) — 64^2 / 32x32 waves
    gemm_bt<64, 64, 2, 2, 2, 2, true, true><<<dim3(Cz / 64, (Bz * Tz) / 64, 1), 256, 0, stream>>>(
        vbf, 0, Cz, Wpb, 0, Cz, (float*)d_out, 0, Cz, bp, Cz, 1.f);
}

// Round 16
// 207.731 us; speedup vs baseline: 1.0777x; 1.0777x over previous
//
#include <hip/hip_runtime.h>
#include <stdint.h>

#define Bz 8
#define Tz 1024
#define Cz 768
#define NHz 12
#define HDz 64

typedef unsigned short u16;
typedef __attribute__((ext_vector_type(8))) __bf16 bf16x8;
typedef __attribute__((ext_vector_type(4))) float f32x4;
typedef __attribute__((ext_vector_type(4))) unsigned int u32x4;

__device__ __forceinline__ float bf2f(u16 b) {
    union { uint32_t u; float f; } c; c.u = ((uint32_t)b) << 16; return c.f;
}
__device__ __forceinline__ u16 f2bf(float f) {
    union { float f; uint32_t u; } c; c.f = f;
    uint32_t u = c.u;
    return (u16)((u + 0x7fffu + ((u >> 16) & 1u)) >> 16);
}
__device__ __forceinline__ u16 f2bf_hw(float f) {   // native RTNE cast
    __bf16 b = (__bf16)f;
    union { __bf16 b; u16 u; } c; c.b = b; return c.u;
}

// s_waitcnt helpers: wait vmcnt<=VM (lgkm/exp unconstrained), and lgkm==0 only.
// simm16 = vm[3:0] | exp(3b)<<4 | lgkm(4b)<<8 | vm[5:4]<<14
template<unsigned VM>
__device__ __forceinline__ void wait_vm() {
    __builtin_amdgcn_s_waitcnt((VM & 15u) | (7u << 4) | (15u << 8) | ((VM >> 4) << 14));
}
__device__ __forceinline__ void wait_lgkm0() {
    __builtin_amdgcn_s_waitcnt(15u | (7u << 4) | (0u << 8) | (3u << 14));
}

// ---------------------------------------------------------------------------
// Fused fp32 -> bf16 elementwise convert for all 4 input tensors (1 launch).
// ---------------------------------------------------------------------------
#define N4_X  (Bz * Tz * Cz / 4)
#define N4_WV (Cz * Cz / 4)
#define N4_WC (Tz * Tz / 4)
#define N4_WP (Cz * Cz / 4)
#define N4_ALL (N4_X + N4_WV + N4_WC + N4_WP)

__global__ __launch_bounds__(256)
void cvt_all(const float* __restrict__ x, const float* __restrict__ wv,
             const float* __restrict__ wc, const float* __restrict__ wp,
             u16* __restrict__ xb, u16* __restrict__ wvb,
             u16* __restrict__ wcb, u16* __restrict__ wpb) {
    int i = blockIdx.x * 256 + threadIdx.x;
    if (i >= N4_ALL) return;
    const float* in;
    u16* out;
    if (i < N4_X) {
        in = x; out = xb;
    } else if (i < N4_X + N4_WV) {
        in = wv; out = wvb; i -= N4_X;
    } else if (i < N4_X + N4_WV + N4_WC) {
        in = wc; out = wcb; i -= N4_X + N4_WV;
    } else {
        in = wp; out = wpb; i -= N4_X + N4_WV + N4_WC;
    }
    float4 v = ((const float4*)in)[i];
    union { u16 h[4]; uint2 u; } o;
    o.h[0] = f2bf(v.x); o.h[1] = f2bf(v.y); o.h[2] = f2bf(v.z); o.h[3] = f2bf(v.w);
    ((uint2*)out)[i] = o.u;
}

// ---------------------------------------------------------------------------
// C = alpha * (A . B^T) [+ bias_col]   MFMA 16x16x32, all-bf16 operands.
// R14 POST-MORTEM: 64^2 block / 32x32-per-wave retile regressed +13us
// (staging bytes/FLOP doubled; these GEMMs are staging-BW-bound, not
// latency-bound). Steps 3/5/7 at the R13-measured optimum:
// 128^2 block, 4 waves of 64x64, BK=64, counted-vmcnt pipeline.
// Step 2 keeps the 4-wave 64^2 variant: same tile, same traffic, 4x TLP
// (1 wave/CU was the R13 config -- pure upside).
//   per iter: ds_read frags -> lgkm0+barrier(WAR) -> stage(t+2) -> MFMA
//   -> vm(LD) -> barrier. No vmcnt(0) drain in steady state.
// A/B staged with global-source chunk XOR swizzle; readers XOR back.
// ---------------------------------------------------------------------------
template<int BM, int BN, int WM, int WN, int MT, int NTC, bool OUTF32, bool HASBIAS>
__global__ __launch_bounds__(WM * WN * 64)
void gemm_bt(const u16* __restrict__ A, long long sAz, int lda,
             const u16* __restrict__ Bp, long long sBz, int ldb,
             void* __restrict__ Cp, long long sCz, int ldc,
             const float* __restrict__ bias, int K, float alpha) {
    constexpr int NT = WM * WN * 64;
    constexpr int BK = 64;
    constexpr int AI = (BM * BK) / (NT * 8);
    constexpr int BI = (BN * BK) / (NT * 8);
    constexpr unsigned LD = AI + BI;           // gload_lds per stage()
    constexpr int WR = MT * 16;                // wave tile rows
    constexpr int WC = NTC * 16;               // wave tile cols
    static_assert(AI >= 1 && (BM * BK) % (NT * 8) == 0, "A staging");
    static_assert(BI >= 1 && (BN * BK) % (NT * 8) == 0, "B staging");
    static_assert(BM == WM * WR && BN == WN * WC, "wave tiling");

    __shared__ alignas(16) u16 As[2][BM * BK];
    __shared__ alignas(16) u16 Bs[2][BN * BK];

    const int z = blockIdx.z;
    const u16* Ag = A + (long long)z * sAz;
    const u16* Bg = Bp + (long long)z * sBz;

    const int tid = threadIdx.x;
    const int lane = tid & 63;
    const int w = tid >> 6;
    const int wm = w / WN;
    const int wn = w % WN;
    const int rowBase = blockIdx.y * BM;
    const int colBase = blockIdx.x * BN;
    const int quad = lane >> 4;
    const int frow = lane & 15;

    auto stage = [&](int buf, int k0) {
#pragma unroll
        for (int i = 0; i < AI; i++) {
            int e = (i * NT + tid) * 8;
            int row = e >> 6;
            int gcol = (((e & 63) >> 3) ^ (row & 7)) * 8;   // src-side swizzle
            const u16* g = Ag + (long long)(rowBase + row) * lda + k0 + gcol;
            __builtin_amdgcn_global_load_lds(
                (const __attribute__((address_space(1))) uint32_t*)g,
                (__attribute__((address_space(3))) uint32_t*)(&As[buf][0] + e), 16, 0, 0);
        }
#pragma unroll
        for (int i = 0; i < BI; i++) {
            int e = (i * NT + tid) * 8;
            int row = e >> 6;
            int gcol = (((e & 63) >> 3) ^ (row & 7)) * 8;
            const u16* g = Bg + (long long)(colBase + row) * ldb + k0 + gcol;
            __builtin_amdgcn_global_load_lds(
                (const __attribute__((address_space(1))) uint32_t*)g,
                (__attribute__((address_space(3))) uint32_t*)(&Bs[buf][0] + e), 16, 0, 0);
        }
    };

    f32x4 acc[MT][NTC] = {};

    const int nk = K / BK;
    stage(0, 0);
    if (nk > 1) { stage(1, BK); wait_vm<LD>(); }   // tile0 landed; tile1 in flight
    else        { wait_vm<0>(); }
    __builtin_amdgcn_s_barrier();                  // all waves' tile0 landed

#pragma unroll 1
    for (int t = 0; t < nk; ++t) {
        const int cur = t & 1;

        // read ALL fragments of tile t into regs
        bf16x8 af[2][MT], bfr[2][NTC];
#pragma unroll
        for (int kk = 0; kk < 2; kk++) {
#pragma unroll
            for (int mt = 0; mt < MT; mt++) {
                int row = wm * WR + mt * 16 + frow;
                af[kk][mt] = *(const bf16x8*)&As[cur][row * 64 + (((kk * 4 + quad) ^ (frow & 7)) * 8)];
            }
#pragma unroll
            for (int nt = 0; nt < NTC; nt++) {
                int row = wn * WC + nt * 16 + frow;
                bfr[kk][nt] = *(const bf16x8*)&Bs[cur][row * 64 + (((kk * 4 + quad) ^ (frow & 7)) * 8)];
            }
        }
        wait_lgkm0();                              // our reads retired to regs
        __builtin_amdgcn_s_barrier();              // all waves done reading buf[cur]

        if (t + 2 < nk) stage(cur, (t + 2) * BK);  // overwrite freed buffer

#pragma unroll
        for (int kk = 0; kk < 2; kk++)
#pragma unroll
            for (int mt = 0; mt < MT; mt++)
#pragma unroll
                for (int nt = 0; nt < NTC; nt++)
                    acc[mt][nt] = __builtin_amdgcn_mfma_f32_16x16x32_bf16(
                        af[kk][mt], bfr[kk][nt], acc[mt][nt], 0, 0, 0);

        if (t + 2 < nk)       wait_vm<LD>();       // tile t+1 landed; t+2 in flight
        else if (t + 1 < nk)  wait_vm<0>();        // last prefetch landed
        if (t + 1 < nk) __builtin_amdgcn_s_barrier();
    }

    const int r0 = rowBase + wm * WR;
    const int c0 = colBase + wn * WC;
    const int rl = (lane >> 4) * 4;
    const int cl = lane & 15;
#pragma unroll
    for (int mt = 0; mt < MT; mt++) {
#pragma unroll
        for (int nt = 0; nt < NTC; nt++) {
#pragma unroll
            for (int r = 0; r < 4; r++) {
                int row = r0 + mt * 16 + rl + r;
                int col = c0 + nt * 16 + cl;
                float v = acc[mt][nt][r] * alpha;
                if (HASBIAS) v += bias[col];
                if (OUTF32)
                    ((float*)Cp)[(long long)z * sCz + (long long)row * ldc + col] = v;
                else
                    ((u16*)Cp)[(long long)z * sCz + (long long)row * ldc + col] = f2bf_hw(v);
            }
        }
    }
}

// ---------------------------------------------------------------------------
// Transpose to bf16: in [rows,cols] (fp32 if INF32 else bf16) -> [cols,rows].
// ---------------------------------------------------------------------------
template<bool INF32>
__global__ __launch_bounds__(256)
void transpose_to_bf16(const void* __restrict__ in, u16* __restrict__ out,
                       int rows, int cols, long long sInZ, long long sOutZ) {
    __shared__ u16 tile[32][33];
    const int z = blockIdx.z;
    const int c0 = blockIdx.x * 32, r0 = blockIdx.y * 32;
    const int tx = threadIdx.x, ty = threadIdx.y;
#pragma unroll
    for (int i = 0; i < 32; i += 8) {
        long long off = (long long)z * sInZ + (long long)(r0 + ty + i) * cols + c0 + tx;
        tile[ty + i][tx] = INF32 ? f2bf(((const float*)in)[off]) : ((const u16*)in)[off];
    }
    __syncthreads();
#pragma unroll
    for (int i = 0; i < 32; i += 8)
        out[(long long)z * sOutZ + (long long)(c0 + ty + i) * rows + r0 + tx] = tile[tx][ty + i];
}

// ---------------------------------------------------------------------------
// Fused flash attention v8 (unchanged; measured 46.8-47.0 across R12/R14).
// ---------------------------------------------------------------------------
#define LOG2E 1.44269504f

__global__ __launch_bounds__(512)
void flash_attn(const u16* __restrict__ v, const u16* __restrict__ U,
                const u16* __restrict__ vT, const float* __restrict__ bc,
                u16* __restrict__ y) {
    __shared__ alignas(16) u16 Us[128 * 64];    // [key][chunk^key&7] (swizzled)
    __shared__ alignas(16) u16 Vs[64 * 128];    // [dim][chunk^dim&15] (swizzled)
    __shared__ alignas(16) u16 Ps[128 * 136];   // q x keys, stride 136
    __shared__ u16 bcs[Tz];                     // bf16(bc * log2e)

    // grid remap: 768 = 8 xcd x 96 slots; xcd-affine columns, heavy qi first
    const int bi = blockIdx.x;
    const int xcd = bi & 7;
    const int slot = bi >> 3;                   // 0..95
    const int col = (slot % 12) * 8 + xcd;      // 0..95, col%8 == xcd
    const int qi = 7 - slot / 12;               // 0..7, heavy tiles first
    const int b = col / NHz, h = col % NHz;

    const int tid = threadIdx.x, lane = tid & 63, w = tid >> 6;
    const int quad = lane >> 4, cl = lane & 15;
    const int q0 = qi * 128;
    const int wrow = w * 16;                    // wave's 16 q-rows (w 0..7)

    for (int j = tid; j < Tz; j += 512) bcs[j] = f2bf(bc[j] * LOG2E);

    // resident A-fragments of vq (this block's own 128x64 slice)
    const u16* vq = v + ((long long)b * Tz + q0) * Cz + h * HDz;
    bf16x8 aS[2];
#pragma unroll
    for (int ks = 0; ks < 2; ks++)
        aS[ks] = *(const bf16x8*)(vq + (long long)(wrow + cl) * Cz + ks * 32 + quad * 8);

    f32x4 Oacc[4] = {};
    float mrow[4], lrow[4];
#pragma unroll
    for (int r = 0; r < 4; r++) { mrow[r] = -3.0e38f; lrow[r] = 0.f; }

    const u16* Ub = U + (long long)b * Tz * Cz + h * HDz;
    const u16* Vb = vT + ((long long)b * Cz + h * HDz) * Tz;

    __syncthreads();   // bcs visible; drains pre-loop VMEM

    const int kts = qi + 1;   // # of 128-wide k-tiles covering [0, q0+128)
    for (int kt = 0; kt < kts; kt++) {
        if (kt) __builtin_amdgcn_s_barrier();   // WAR: all waves done with Us/Vs
        const u16* Ug = Ub + (long long)kt * 128 * Cz;
#pragma unroll
        for (int i = 0; i < 2; i++) {           // Us first (waited by vmcnt(2))
            int e = (i * 512 + tid) * 8;
            int key = e >> 6;
            int ch = ((e & 63) >> 3) ^ (key & 7);   // global-side swizzle
            __builtin_amdgcn_global_load_lds(
                (const __attribute__((address_space(1))) uint32_t*)(Ug + (long long)key * Cz + ch * 8),
                (__attribute__((address_space(3))) uint32_t*)(Us + e), 16, 0, 0);
        }
        const u16* Vg = Vb + kt * 128;
#pragma unroll
        for (int i = 0; i < 2; i++) {           // Vs second (stays in flight)
            int e = (i * 512 + tid) * 8;
            int dim = e >> 7;
            int ch = ((e & 127) >> 3) ^ (dim & 15);  // global-side swizzle
            __builtin_amdgcn_global_load_lds(
                (const __attribute__((address_space(1))) uint32_t*)(Vg + (long long)dim * Tz + ch * 8),
                (__attribute__((address_space(3))) uint32_t*)(Vs + e), 16, 0, 0);
        }
        // own Us landed (in-order retire); Vs (newest 2) may still be in flight
        asm volatile("s_waitcnt vmcnt(2)" ::: "memory");
        __builtin_amdgcn_s_barrier();           // all waves' Us landed

        // S = vq . Uk^T  (wave tile 16 x 128) — overlaps Vs flight time
        f32x4 S[8] = {};
        __builtin_amdgcn_s_setprio(1);
#pragma unroll
        for (int ks = 0; ks < 2; ks++)
#pragma unroll
            for (int nt = 0; nt < 8; nt++) {
                int key = nt * 16 + cl;
                bf16x8 bS = *(const bf16x8*)&Us[key * 64 + (((ks * 4 + quad) ^ (key & 7)) * 8)];
                S[nt] = __builtin_amdgcn_mfma_f32_16x16x32_bf16(aS[ks], bS, S[nt], 0, 0, 0);
            }
        __builtin_amdgcn_s_setprio(0);

        const bool last = (kt == kts - 1);
#pragma unroll
        for (int nt = 0; nt < 8; nt++) {
            float bl = bf2f(bcs[kt * 128 + nt * 16 + cl]);
#pragma unroll
            for (int r = 0; r < 4; r++)
                S[nt][r] = S[nt][r] * (0.125f * LOG2E) + bl;
        }
        if (last) {                             // uniform branch: mask fixup
            int rowg = q0 + wrow + quad * 4;
#pragma unroll
            for (int nt = 0; nt < 8; nt++) {
                int colg = kt * 128 + nt * 16 + cl;
#pragma unroll
                for (int r = 0; r < 4; r++)
                    if (colg > rowg + r) S[nt][r] = -3.0e38f;
            }
        }

        // row max (regs, then across the 16 lanes of the quad group)
        float mnew[4], alpha[4];
#pragma unroll
        for (int r = 0; r < 4; r++) {
            float m = S[0][r];
#pragma unroll
            for (int nt = 1; nt < 8; nt++) m = fmaxf(m, S[nt][r]);
#pragma unroll
            for (int d = 1; d < 16; d <<= 1) m = fmaxf(m, __shfl_xor(m, d));
            mnew[r] = fmaxf(mrow[r], m);
            alpha[r] = __builtin_amdgcn_exp2f(mrow[r] - mnew[r]);
            mrow[r] = mnew[r];
        }

        // P = exp2(S - m) -> LDS (wave-private rows), accumulate row sums
        float psum[4] = {};
#pragma unroll
        for (int nt = 0; nt < 8; nt++)
#pragma unroll
            for (int r = 0; r < 4; r++) {
                float p = __builtin_amdgcn_exp2f(S[nt][r] - mnew[r]);
                psum[r] += p;
                Ps[(wrow + quad * 4 + r) * 136 + nt * 16 + cl] = f2bf_hw(p);
            }
#pragma unroll
        for (int r = 0; r < 4; r++) {
            float s = psum[r];
#pragma unroll
            for (int d = 1; d < 16; d <<= 1) s += __shfl_xor(s, d);
            lrow[r] = lrow[r] * alpha[r] + s;
#pragma unroll
            for (int nt2 = 0; nt2 < 4; nt2++)
                Oacc[nt2][r] *= alpha[r];
        }

        // own Vs landed; barrier -> all waves' Vs landed
        asm volatile("s_waitcnt vmcnt(0)" ::: "memory");
        __builtin_amdgcn_s_barrier();

        // O += P . Vk   (K = 128)
        __builtin_amdgcn_s_setprio(1);
#pragma unroll
        for (int ks = 0; ks < 4; ks++) {
            bf16x8 pA = *(const bf16x8*)&Ps[(wrow + cl) * 136 + ks * 32 + quad * 8];
#pragma unroll
            for (int nt2 = 0; nt2 < 4; nt2++) {
                int dim = nt2 * 16 + cl;
                bf16x8 vB = *(const bf16x8*)&Vs[dim * 128 + (((ks * 4 + quad) ^ cl) * 8)];
                Oacc[nt2] = __builtin_amdgcn_mfma_f32_16x16x32_bf16(pA, vB, Oacc[nt2], 0, 0, 0);
            }
        }
        __builtin_amdgcn_s_setprio(0);
    }

    // epilogue: O /= l, write y (in-place into v's own region)
    u16* yq = y + ((long long)b * Tz + q0) * Cz + h * HDz;
#pragma unroll
    for (int r = 0; r < 4; r++) {
        float inv = 1.f / lrow[r];
#pragma unroll
        for (int nt2 = 0; nt2 < 4; nt2++)
            yq[(long long)(wrow + quad * 4 + r) * Cz + nt2 * 16 + cl] =
                f2bf_hw(Oacc[nt2][r] * inv);
    }
}

// ---------------------------------------------------------------------------
extern "C" void kernel_launch(void* const* d_in, const int* in_sizes, int n_in,
                              void* d_out, int out_size, void* d_ws, size_t ws_size,
                              hipStream_t stream) {
    const float* x  = (const float*)d_in[0];
    const float* Wv = (const float*)d_in[1];
    const float* bv = (const float*)d_in[2];
    const float* Wl = (const float*)d_in[3];
    const float* Wc = (const float*)d_in[4];
    const float* bc = (const float*)d_in[5];
    const float* Wp = (const float*)d_in[6];
    const float* bp = (const float*)d_in[7];

    // ws (bf16 elems, ~59 MB): xb, Wvb, Wcb, Wpb, WlT, Wcl, vbf, vT, U
    u16* ws  = (u16*)d_ws;
    u16* xb  = ws;
    u16* Wvb = xb  + (size_t)Bz * Tz * Cz;
    u16* Wcb = Wvb + (size_t)Cz * Cz;
    u16* Wpb = Wcb + (size_t)Tz * Tz;
    u16* WlT = Wpb + (size_t)Cz * Cz;
    u16* Wcl = WlT + (size_t)Tz * Tz;
    u16* vbf = Wcl + (size_t)Tz * Tz;
    u16* vT  = vbf + (size_t)Bz * Tz * Cz;
    u16* U   = vT  + (size_t)Bz * Tz * Cz;

    const long long sTC = (long long)Tz * Cz;
    const long long sCT = (long long)Cz * Tz;

    // 0) one-time bf16 conversions (single fused launch)
    cvt_all<<<(N4_ALL + 255) / 256, 256, 0, stream>>>(x, Wv, Wc, Wp, xb, Wvb, Wcb, Wpb);
    // 1) WlT = Wl^T (fp32 -> bf16)
    transpose_to_bf16<true><<<dim3(32, 32, 1), dim3(32, 8), 0, stream>>>(Wl, WlT, Tz, Tz, 0, 0);
    // 2) Wcl = Wcb . WlT^T = Wc @ Wl — 64^2 block / 4 waves of 32x32
    //    (same tile+traffic as R13's 1-wave config, 4x TLP)
    gemm_bt<64, 64, 2, 2, 2, 2, false, false><<<dim3(Tz / 64, Tz / 64, 1), 256, 0, stream>>>(
        Wcb, 0, Tz, WlT, 0, Tz, Wcl, 0, Tz, nullptr, Tz, 1.f);
    // 3) v = xb . Wvb^T + bv — 128^2 / 64x64 waves (R13-measured optimum)
    gemm_bt<128, 128, 2, 2, 4, 4, false, true><<<dim3(Cz / 128, (Bz * Tz) / 128, 1), 256, 0, stream>>>(
        xb, 0, Cz, Wvb, 0, Cz, vbf, 0, Cz, bv, Cz, 1.f);
    // 4) vT[b] = v[b]^T
    transpose_to_bf16<false><<<dim3(Cz / 32, Tz / 32, Bz), dim3(32, 8), 0, stream>>>(
        vbf, vT, Tz, Cz, sTC, sCT);
    // 5) U[b] = Wcl @ v[b]  (= Wcl . vT[b]^T), K=T — 128^2 / 64x64 waves
    gemm_bt<128, 128, 2, 2, 4, 4, false, false><<<dim3(Cz / 128, Tz / 128, Bz), 256, 0, stream>>>(
        Wcl, 0, Tz, vT, sCT, Tz, U, sTC, Cz, nullptr, Tz, 1.f);
    // 6) fused logits -> causal softmax -> P.V, y in-place into vbf
    flash_attn<<<dim3(8 * NHz * Bz, 1, 1), 512, 0, stream>>>(vbf, U, vT, bc, vbf);
    // 7) out = y . Wpb^T + bp  (fp32 out) — 128^2 / 64x64 waves
    gemm_bt<128, 128, 2, 2, 4, 4, true, true><<<dim3(Cz / 128, (Bz * Tz) / 128, 1), 256, 0, stream>>>(
        vbf, 0, Cz, Wpb, 0, Cz, (float*)d_out, 0, Cz, bp, Cz, 1.f);
}

// Round 19
// 207.705 us; speedup vs baseline: 1.0778x; 1.0001x over previous
//
#include <hip/hip_runtime.h>
#include <stdint.h>

#define Bz 8
#define Tz 1024
#define Cz 768
#define NHz 12
#define HDz 64

typedef unsigned short u16;
typedef __attribute__((ext_vector_type(8))) __bf16 bf16x8;
typedef __attribute__((ext_vector_type(4))) float f32x4;
typedef __attribute__((ext_vector_type(4))) unsigned int u32x4;

__device__ __forceinline__ float bf2f(u16 b) {
    union { uint32_t u; float f; } c; c.u = ((uint32_t)b) << 16; return c.f;
}
__device__ __forceinline__ u16 f2bf(float f) {
    union { float f; uint32_t u; } c; c.f = f;
    uint32_t u = c.u;
    return (u16)((u + 0x7fffu + ((u >> 16) & 1u)) >> 16);
}
__device__ __forceinline__ u16 f2bf_hw(float f) {   // native RTNE cast
    __bf16 b = (__bf16)f;
    union { __bf16 b; u16 u; } c; c.b = b; return c.u;
}

// s_waitcnt helpers: wait vmcnt<=VM (lgkm/exp unconstrained), and lgkm==0 only.
// simm16 = vm[3:0] | exp(3b)<<4 | lgkm(4b)<<8 | vm[5:4]<<14
template<unsigned VM>
__device__ __forceinline__ void wait_vm() {
    __builtin_amdgcn_s_waitcnt((VM & 15u) | (7u << 4) | (15u << 8) | ((VM >> 4) << 14));
}
__device__ __forceinline__ void wait_lgkm0() {
    __builtin_amdgcn_s_waitcnt(15u | (7u << 4) | (0u << 8) | (3u << 14));
}

// ---------------------------------------------------------------------------
// Fused fp32 -> bf16 elementwise convert for all 4 input tensors (1 launch).
// ---------------------------------------------------------------------------
#define N4_X  (Bz * Tz * Cz / 4)
#define N4_WV (Cz * Cz / 4)
#define N4_WC (Tz * Tz / 4)
#define N4_WP (Cz * Cz / 4)
#define N4_ALL (N4_X + N4_WV + N4_WC + N4_WP)

__global__ __launch_bounds__(256)
void cvt_all(const float* __restrict__ x, const float* __restrict__ wv,
             const float* __restrict__ wc, const float* __restrict__ wp,
             u16* __restrict__ xb, u16* __restrict__ wvb,
             u16* __restrict__ wcb, u16* __restrict__ wpb) {
    int i = blockIdx.x * 256 + threadIdx.x;
    if (i >= N4_ALL) return;
    const float* in;
    u16* out;
    if (i < N4_X) {
        in = x; out = xb;
    } else if (i < N4_X + N4_WV) {
        in = wv; out = wvb; i -= N4_X;
    } else if (i < N4_X + N4_WV + N4_WC) {
        in = wc; out = wcb; i -= N4_X + N4_WV;
    } else {
        in = wp; out = wpb; i -= N4_X + N4_WV + N4_WC;
    }
    float4 v = ((const float4*)in)[i];
    union { u16 h[4]; uint2 u; } o;
    o.h[0] = f2bf(v.x); o.h[1] = f2bf(v.y); o.h[2] = f2bf(v.z); o.h[3] = f2bf(v.w);
    ((uint2*)out)[i] = o.u;
}

// ---------------------------------------------------------------------------
// C = alpha * (A . B^T) [+ bias_col]   MFMA 16x16x32, all-bf16 operands.
// R16 change: BN 128 -> 96 for the big GEMMs. Grid 384 (1.5 blocks/CU,
// 128 CUs carrying double load) -> 512 (exactly 2.0/CU, even residency).
// Staging bytes/FLOP +17% (vs R14's +100% and R9's +50%, both losses) --
// operands are L2-resident, balance gain should dominate.
// BK=64 + counted-vmcnt pipeline (R13-measured win):
//   per iter: ds_read frags -> lgkm0+barrier(WAR) -> stage(t+2) -> MFMA
//   -> vm(LD) -> barrier. No vmcnt(0) drain in steady state.
// A/B staged with global-source chunk XOR swizzle; readers XOR back
// (valid: WR,WC multiples of 8 -> row&7 == frow&7).
// ---------------------------------------------------------------------------
template<int BM, int BN, int WM, int WN, int MT, int NTC, bool OUTF32, bool HASBIAS>
__global__ __launch_bounds__(WM * WN * 64)
void gemm_bt(const u16* __restrict__ A, long long sAz, int lda,
             const u16* __restrict__ Bp, long long sBz, int ldb,
             void* __restrict__ Cp, long long sCz, int ldc,
             const float* __restrict__ bias, int K, float alpha) {
    constexpr int NT = WM * WN * 64;
    constexpr int BK = 64;
    constexpr int AI = (BM * BK) / (NT * 8);
    constexpr int BI = (BN * BK) / (NT * 8);
    constexpr unsigned LD = AI + BI;           // gload_lds per stage()
    constexpr int WR = MT * 16;                // wave tile rows
    constexpr int WC = NTC * 16;               // wave tile cols
    static_assert(AI >= 1 && (BM * BK) % (NT * 8) == 0, "A staging");
    static_assert(BI >= 1 && (BN * BK) % (NT * 8) == 0, "B staging");
    static_assert(BM == WM * WR && BN == WN * WC, "wave tiling");
    static_assert((WR % 8) == 0 && (WC % 16) == 0, "swizzle validity");

    __shared__ alignas(16) u16 As[2][BM * BK];
    __shared__ alignas(16) u16 Bs[2][BN * BK];

    const int z = blockIdx.z;
    const u16* Ag = A + (long long)z * sAz;
    const u16* Bg = Bp + (long long)z * sBz;

    const int tid = threadIdx.x;
    const int lane = tid & 63;
    const int w = tid >> 6;
    const int wm = w / WN;
    const int wn = w % WN;
    const int rowBase = blockIdx.y * BM;
    const int colBase = blockIdx.x * BN;
    const int quad = lane >> 4;
    const int frow = lane & 15;

    auto stage = [&](int buf, int k0) {
#pragma unroll
        for (int i = 0; i < AI; i++) {
            int e = (i * NT + tid) * 8;
            int row = e >> 6;
            int gcol = (((e & 63) >> 3) ^ (row & 7)) * 8;   // src-side swizzle
            const u16* g = Ag + (long long)(rowBase + row) * lda + k0 + gcol;
            __builtin_amdgcn_global_load_lds(
                (const __attribute__((address_space(1))) uint32_t*)g,
                (__attribute__((address_space(3))) uint32_t*)(&As[buf][0] + e), 16, 0, 0);
        }
#pragma unroll
        for (int i = 0; i < BI; i++) {
            int e = (i * NT + tid) * 8;
            int row = e >> 6;
            int gcol = (((e & 63) >> 3) ^ (row & 7)) * 8;
            const u16* g = Bg + (long long)(colBase + row) * ldb + k0 + gcol;
            __builtin_amdgcn_global_load_lds(
                (const __attribute__((address_space(1))) uint32_t*)g,
                (__attribute__((address_space(3))) uint32_t*)(&Bs[buf][0] + e), 16, 0, 0);
        }
    };

    f32x4 acc[MT][NTC] = {};

    const int nk = K / BK;
    stage(0, 0);
    if (nk > 1) { stage(1, BK); wait_vm<LD>(); }   // tile0 landed; tile1 in flight
    else        { wait_vm<0>(); }
    __builtin_amdgcn_s_barrier();                  // all waves' tile0 landed

#pragma unroll 1
    for (int t = 0; t < nk; ++t) {
        const int cur = t & 1;

        // read ALL fragments of tile t into regs
        bf16x8 af[2][MT], bfr[2][NTC];
#pragma unroll
        for (int kk = 0; kk < 2; kk++) {
#pragma unroll
            for (int mt = 0; mt < MT; mt++) {
                int row = wm * WR + mt * 16 + frow;
                af[kk][mt] = *(const bf16x8*)&As[cur][row * 64 + (((kk * 4 + quad) ^ (frow & 7)) * 8)];
            }
#pragma unroll
            for (int nt = 0; nt < NTC; nt++) {
                int row = wn * WC + nt * 16 + frow;
                bfr[kk][nt] = *(const bf16x8*)&Bs[cur][row * 64 + (((kk * 4 + quad) ^ (frow & 7)) * 8)];
            }
        }
        wait_lgkm0();                              // our reads retired to regs
        __builtin_amdgcn_s_barrier();              // all waves done reading buf[cur]

        if (t + 2 < nk) stage(cur, (t + 2) * BK);  // overwrite freed buffer

#pragma unroll
        for (int kk = 0; kk < 2; kk++)
#pragma unroll
            for (int mt = 0; mt < MT; mt++)
#pragma unroll
                for (int nt = 0; nt < NTC; nt++)
                    acc[mt][nt] = __builtin_amdgcn_mfma_f32_16x16x32_bf16(
                        af[kk][mt], bfr[kk][nt], acc[mt][nt], 0, 0, 0);

        if (t + 2 < nk)       wait_vm<LD>();       // tile t+1 landed; t+2 in flight
        else if (t + 1 < nk)  wait_vm<0>();        // last prefetch landed
        if (t + 1 < nk) __builtin_amdgcn_s_barrier();
    }

    const int r0 = rowBase + wm * WR;
    const int c0 = colBase + wn * WC;
    const int rl = (lane >> 4) * 4;
    const int cl = lane & 15;
#pragma unroll
    for (int mt = 0; mt < MT; mt++) {
#pragma unroll
        for (int nt = 0; nt < NTC; nt++) {
#pragma unroll
            for (int r = 0; r < 4; r++) {
                int row = r0 + mt * 16 + rl + r;
                int col = c0 + nt * 16 + cl;
                float v = acc[mt][nt][r] * alpha;
                if (HASBIAS) v += bias[col];
                if (OUTF32)
                    ((float*)Cp)[(long long)z * sCz + (long long)row * ldc + col] = v;
                else
                    ((u16*)Cp)[(long long)z * sCz + (long long)row * ldc + col] = f2bf_hw(v);
            }
        }
    }
}

// ---------------------------------------------------------------------------
// Transpose to bf16: in [rows,cols] (fp32 if INF32 else bf16) -> [cols,rows].
// ---------------------------------------------------------------------------
template<bool INF32>
__global__ __launch_bounds__(256)
void transpose_to_bf16(const void* __restrict__ in, u16* __restrict__ out,
                       int rows, int cols, long long sInZ, long long sOutZ) {
    __shared__ u16 tile[32][33];
    const int z = blockIdx.z;
    const int c0 = blockIdx.x * 32, r0 = blockIdx.y * 32;
    const int tx = threadIdx.x, ty = threadIdx.y;
#pragma unroll
    for (int i = 0; i < 32; i += 8) {
        long long off = (long long)z * sInZ + (long long)(r0 + ty + i) * cols + c0 + tx;
        tile[ty + i][tx] = INF32 ? f2bf(((const float*)in)[off]) : ((const u16*)in)[off];
    }
    __syncthreads();
#pragma unroll
    for (int i = 0; i < 32; i += 8)
        out[(long long)z * sOutZ + (long long)(c0 + ty + i) * rows + r0 + tx] = tile[tx][ty + i];
}

// ---------------------------------------------------------------------------
// Fused flash attention v8 (unchanged; measured 46.6-47.0 across R12-R16).
// ---------------------------------------------------------------------------
#define LOG2E 1.44269504f

__global__ __launch_bounds__(512)
void flash_attn(const u16* __restrict__ v, const u16* __restrict__ U,
                const u16* __restrict__ vT, const float* __restrict__ bc,
                u16* __restrict__ y) {
    __shared__ alignas(16) u16 Us[128 * 64];    // [key][chunk^key&7] (swizzled)
    __shared__ alignas(16) u16 Vs[64 * 128];    // [dim][chunk^dim&15] (swizzled)
    __shared__ alignas(16) u16 Ps[128 * 136];   // q x keys, stride 136
    __shared__ u16 bcs[Tz];                     // bf16(bc * log2e)

    // grid remap: 768 = 8 xcd x 96 slots; xcd-affine columns, heavy qi first
    const int bi = blockIdx.x;
    const int xcd = bi & 7;
    const int slot = bi >> 3;                   // 0..95
    const int col = (slot % 12) * 8 + xcd;      // 0..95, col%8 == xcd
    const int qi = 7 - slot / 12;               // 0..7, heavy tiles first
    const int b = col / NHz, h = col % NHz;

    const int tid = threadIdx.x, lane = tid & 63, w = tid >> 6;
    const int quad = lane >> 4, cl = lane & 15;
    const int q0 = qi * 128;
    const int wrow = w * 16;                    // wave's 16 q-rows (w 0..7)

    for (int j = tid; j < Tz; j += 512) bcs[j] = f2bf(bc[j] * LOG2E);

    // resident A-fragments of vq (this block's own 128x64 slice)
    const u16* vq = v + ((long long)b * Tz + q0) * Cz + h * HDz;
    bf16x8 aS[2];
#pragma unroll
    for (int ks = 0; ks < 2; ks++)
        aS[ks] = *(const bf16x8*)(vq + (long long)(wrow + cl) * Cz + ks * 32 + quad * 8);

    f32x4 Oacc[4] = {};
    float mrow[4], lrow[4];
#pragma unroll
    for (int r = 0; r < 4; r++) { mrow[r] = -3.0e38f; lrow[r] = 0.f; }

    const u16* Ub = U + (long long)b * Tz * Cz + h * HDz;
    const u16* Vb = vT + ((long long)b * Cz + h * HDz) * Tz;

    __syncthreads();   // bcs visible; drains pre-loop VMEM

    const int kts = qi + 1;   // # of 128-wide k-tiles covering [0, q0+128)
    for (int kt = 0; kt < kts; kt++) {
        if (kt) __builtin_amdgcn_s_barrier();   // WAR: all waves done with Us/Vs
        const u16* Ug = Ub + (long long)kt * 128 * Cz;
#pragma unroll
        for (int i = 0; i < 2; i++) {           // Us first (waited by vmcnt(2))
            int e = (i * 512 + tid) * 8;
            int key = e >> 6;
            int ch = ((e & 63) >> 3) ^ (key & 7);   // global-side swizzle
            __builtin_amdgcn_global_load_lds(
                (const __attribute__((address_space(1))) uint32_t*)(Ug + (long long)key * Cz + ch * 8),
                (__attribute__((address_space(3))) uint32_t*)(Us + e), 16, 0, 0);
        }
        const u16* Vg = Vb + kt * 128;
#pragma unroll
        for (int i = 0; i < 2; i++) {           // Vs second (stays in flight)
            int e = (i * 512 + tid) * 8;
            int dim = e >> 7;
            int ch = ((e & 127) >> 3) ^ (dim & 15);  // global-side swizzle
            __builtin_amdgcn_global_load_lds(
                (const __attribute__((address_space(1))) uint32_t*)(Vg + (long long)dim * Tz + ch * 8),
                (__attribute__((address_space(3))) uint32_t*)(Vs + e), 16, 0, 0);
        }
        // own Us landed (in-order retire); Vs (newest 2) may still be in flight
        asm volatile("s_waitcnt vmcnt(2)" ::: "memory");
        __builtin_amdgcn_s_barrier();           // all waves' Us landed

        // S = vq . Uk^T  (wave tile 16 x 128) — overlaps Vs flight time
        f32x4 S[8] = {};
        __builtin_amdgcn_s_setprio(1);
#pragma unroll
        for (int ks = 0; ks < 2; ks++)
#pragma unroll
            for (int nt = 0; nt < 8; nt++) {
                int key = nt * 16 + cl;
                bf16x8 bS = *(const bf16x8*)&Us[key * 64 + (((ks * 4 + quad) ^ (key & 7)) * 8)];
                S[nt] = __builtin_amdgcn_mfma_f32_16x16x32_bf16(aS[ks], bS, S[nt], 0, 0, 0);
            }
        __builtin_amdgcn_s_setprio(0);

        const bool last = (kt == kts - 1);
#pragma unroll
        for (int nt = 0; nt < 8; nt++) {
            float bl = bf2f(bcs[kt * 128 + nt * 16 + cl]);
#pragma unroll
            for (int r = 0; r < 4; r++)
                S[nt][r] = S[nt][r] * (0.125f * LOG2E) + bl;
        }
        if (last) {                             // uniform branch: mask fixup
            int rowg = q0 + wrow + quad * 4;
#pragma unroll
            for (int nt = 0; nt < 8; nt++) {
                int colg = kt * 128 + nt * 16 + cl;
#pragma unroll
                for (int r = 0; r < 4; r++)
                    if (colg > rowg + r) S[nt][r] = -3.0e38f;
            }
        }

        // row max (regs, then across the 16 lanes of the quad group)
        float mnew[4], alpha[4];
#pragma unroll
        for (int r = 0; r < 4; r++) {
            float m = S[0][r];
#pragma unroll
            for (int nt = 1; nt < 8; nt++) m = fmaxf(m, S[nt][r]);
#pragma unroll
            for (int d = 1; d < 16; d <<= 1) m = fmaxf(m, __shfl_xor(m, d));
            mnew[r] = fmaxf(mrow[r], m);
            alpha[r] = __builtin_amdgcn_exp2f(mrow[r] - mnew[r]);
            mrow[r] = mnew[r];
        }

        // P = exp2(S - m) -> LDS (wave-private rows), accumulate row sums
        float psum[4] = {};
#pragma unroll
        for (int nt = 0; nt < 8; nt++)
#pragma unroll
            for (int r = 0; r < 4; r++) {
                float p = __builtin_amdgcn_exp2f(S[nt][r] - mnew[r]);
                psum[r] += p;
                Ps[(wrow + quad * 4 + r) * 136 + nt * 16 + cl] = f2bf_hw(p);
            }
#pragma unroll
        for (int r = 0; r < 4; r++) {
            float s = psum[r];
#pragma unroll
            for (int d = 1; d < 16; d <<= 1) s += __shfl_xor(s, d);
            lrow[r] = lrow[r] * alpha[r] + s;
#pragma unroll
            for (int nt2 = 0; nt2 < 4; nt2++)
                Oacc[nt2][r] *= alpha[r];
        }

        // own Vs landed; barrier -> all waves' Vs landed
        asm volatile("s_waitcnt vmcnt(0)" ::: "memory");
        __builtin_amdgcn_s_barrier();

        // O += P . Vk   (K = 128)
        __builtin_amdgcn_s_setprio(1);
#pragma unroll
        for (int ks = 0; ks < 4; ks++) {
            bf16x8 pA = *(const bf16x8*)&Ps[(wrow + cl) * 136 + ks * 32 + quad * 8];
#pragma unroll
            for (int nt2 = 0; nt2 < 4; nt2++) {
                int dim = nt2 * 16 + cl;
                bf16x8 vB = *(const bf16x8*)&Vs[dim * 128 + (((ks * 4 + quad) ^ cl) * 8)];
                Oacc[nt2] = __builtin_amdgcn_mfma_f32_16x16x32_bf16(pA, vB, Oacc[nt2], 0, 0, 0);
            }
        }
        __builtin_amdgcn_s_setprio(0);
    }

    // epilogue: O /= l, write y (in-place into v's own region)
    u16* yq = y + ((long long)b * Tz + q0) * Cz + h * HDz;
#pragma unroll
    for (int r = 0; r < 4; r++) {
        float inv = 1.f / lrow[r];
#pragma unroll
        for (int nt2 = 0; nt2 < 4; nt2++)
            yq[(long long)(wrow + quad * 4 + r) * Cz + nt2 * 16 + cl] =
                f2bf_hw(Oacc[nt2][r] * inv);
    }
}

// ---------------------------------------------------------------------------
extern "C" void kernel_launch(void* const* d_in, const int* in_sizes, int n_in,
                              void* d_out, int out_size, void* d_ws, size_t ws_size,
                              hipStream_t stream) {
    const float* x  = (const float*)d_in[0];
    const float* Wv = (const float*)d_in[1];
    const float* bv = (const float*)d_in[2];
    const float* Wl = (const float*)d_in[3];
    const float* Wc = (const float*)d_in[4];
    const float* bc = (const float*)d_in[5];
    const float* Wp = (const float*)d_in[6];
    const float* bp = (const float*)d_in[7];

    // ws (bf16 elems, ~59 MB): xb, Wvb, Wcb, Wpb, WlT, Wcl, vbf, vT, U
    u16* ws  = (u16*)d_ws;
    u16* xb  = ws;
    u16* Wvb = xb  + (size_t)Bz * Tz * Cz;
    u16* Wcb = Wvb + (size_t)Cz * Cz;
    u16* Wpb = Wcb + (size_t)Tz * Tz;
    u16* WlT = Wpb + (size_t)Cz * Cz;
    u16* Wcl = WlT + (size_t)Tz * Tz;
    u16* vbf = Wcl + (size_t)Tz * Tz;
    u16* vT  = vbf + (size_t)Bz * Tz * Cz;
    u16* U   = vT  + (size_t)Bz * Tz * Cz;

    const long long sTC = (long long)Tz * Cz;
    const long long sCT = (long long)Cz * Tz;

    // 0) one-time bf16 conversions (single fused launch)
    cvt_all<<<(N4_ALL + 255) / 256, 256, 0, stream>>>(x, Wv, Wc, Wp, xb, Wvb, Wcb, Wpb);
    // 1) WlT = Wl^T (fp32 -> bf16)
    transpose_to_bf16<true><<<dim3(32, 32, 1), dim3(32, 8), 0, stream>>>(Wl, WlT, Tz, Tz, 0, 0);
    // 2) Wcl = Wcb . WlT^T = Wc @ Wl — 64^2 block / 4 waves of 32x32
    gemm_bt<64, 64, 2, 2, 2, 2, false, false><<<dim3(Tz / 64, Tz / 64, 1), 256, 0, stream>>>(
        Wcb, 0, Tz, WlT, 0, Tz, Wcl, 0, Tz, nullptr, Tz, 1.f);
    // 3) v = xb . Wvb^T + bv — 128x96 tile: 512 blocks = 2.0/CU even
    gemm_bt<128, 96, 2, 2, 4, 3, false, true><<<dim3(Cz / 96, (Bz * Tz) / 128, 1), 256, 0, stream>>>(
        xb, 0, Cz, Wvb, 0, Cz, vbf, 0, Cz, bv, Cz, 1.f);
    // 4) vT[b] = v[b]^T
    transpose_to_bf16<false><<<dim3(Cz / 32, Tz / 32, Bz), dim3(32, 8), 0, stream>>>(
        vbf, vT, Tz, Cz, sTC, sCT);
    // 5) U[b] = Wcl @ v[b]  (= Wcl . vT[b]^T), K=T — 128x96: 512 blocks
    gemm_bt<128, 96, 2, 2, 4, 3, false, false><<<dim3(Cz / 96, Tz / 128, Bz), 256, 0, stream>>>(
        Wcl, 0, Tz, vT, sCT, Tz, U, sTC, Cz, nullptr, Tz, 1.f);
    // 6) fused logits -> causal softmax -> P.V, y in-place into vbf
    flash_attn<<<dim3(8 * NHz * Bz, 1, 1), 512, 0, stream>>>(vbf, U, vT, bc, vbf);
    // 7) out = y . Wpb^T + bp  (fp32 out) — 128x96: 512 blocks
    gemm_bt<128, 96, 2, 2, 4, 3, true, true><<<dim3(Cz / 96, (Bz * Tz) / 128, 1), 256, 0, stream>>>(
        vbf, 0, Cz, Wpb, 0, Cz, (float*)d_out, 0, Cz, bp, Cz, 1.f);
}